// Round 5
// baseline (154.833 us; speedup 1.0000x reference)
//
#include <hip/hip_runtime.h>
#include <hip/hip_bf16.h>

// ToneMappingCurveLoss — DIAGNOSTIC ROUND: ablation ladder + correct output.
// Inputs: pred, target, input_img: [16, 3, 512, 512] f32. Output: 1 f32 scalar.

#define CH4 65536         // HW/4 (float4 groups per channel)
#define NBINS 16
#define NCOL (3 * NBINS)

__device__ __forceinline__ float luma_exact(float r, float g, float b) {
    return __fadd_rn(__fadd_rn(__fmul_rn(0.299f, r), __fmul_rn(0.587f, g)),
                     __fmul_rn(0.114f, b));
}

// ---------- ablation 1: pure linear read, 3 streams ----------
__global__ __launch_bounds__(256) void ab_read3(
    const float4* __restrict__ a, const float4* __restrict__ b,
    const float4* __restrict__ c, float* __restrict__ ws, int n4)
{
    float s = 0.0f;
    const int T = gridDim.x * 256;
    for (int k = blockIdx.x * 256 + threadIdx.x; k < n4; k += T) {
        const float4 x = a[k], y = b[k], z = c[k];
        s += x.x + x.y + x.z + x.w + y.x + y.y + y.z + y.w
           + z.x + z.y + z.z + z.w;
    }
    #pragma unroll
    for (int o = 32; o; o >>= 1) s += __shfl_down(s, o);
    if ((threadIdx.x & 63) == 0) ws[blockIdx.x * 4 + (threadIdx.x >> 6)] = s;
}

// ---------- ablation 2: stage1's 9-stream pattern, pure read ----------
__global__ __launch_bounds__(256) void ab_read9(
    const float4* __restrict__ pred, const float4* __restrict__ target,
    const float4* __restrict__ input, float* __restrict__ ws, int G)
{
    float s = 0.0f;
    const int T = gridDim.x * 256;
    for (int g = blockIdx.x * 256 + threadIdx.x; g < G; g += T) {
        const int a = (g >> 16) * (3 * CH4) + (g & (CH4 - 1));
        const float4 i0 = input[a],  i1 = input[a + CH4],  i2 = input[a + 2 * CH4];
        const float4 p0 = pred[a],   p1 = pred[a + CH4],   p2 = pred[a + 2 * CH4];
        const float4 t0 = target[a], t1 = target[a + CH4], t2 = target[a + 2 * CH4];
        s += i0.x + i0.y + i0.z + i0.w + i1.x + i1.y + i1.z + i1.w
           + i2.x + i2.y + i2.z + i2.w + p0.x + p0.y + p0.z + p0.w
           + p1.x + p1.y + p1.z + p1.w + p2.x + p2.y + p2.z + p2.w
           + t0.x + t0.y + t0.z + t0.w + t1.x + t1.y + t1.z + t1.w
           + t2.x + t2.y + t2.z + t2.w;
    }
    #pragma unroll
    for (int o = 32; o; o >>= 1) s += __shfl_down(s, o);
    if ((threadIdx.x & 63) == 0) ws[blockIdx.x * 4 + (threadIdx.x >> 6)] = s;
}

// ---------- ablation 3: full compute, NO LDS atomics ----------
__global__ __launch_bounds__(256) void ab_nolds(
    const float4* __restrict__ pred, const float4* __restrict__ target,
    const float4* __restrict__ input, float* __restrict__ ws, int G)
{
    float s = 0.0f;
    const int T = gridDim.x * 256;
    for (int g = blockIdx.x * 256 + threadIdx.x; g < G; g += T) {
        const int a = (g >> 16) * (3 * CH4) + (g & (CH4 - 1));
        const float4 i0 = input[a],  i1 = input[a + CH4],  i2 = input[a + 2 * CH4];
        const float4 p0 = pred[a],   p1 = pred[a + CH4],   p2 = pred[a + 2 * CH4];
        const float4 t0 = target[a], t1 = target[a + CH4], t2 = target[a + 2 * CH4];
        const float ir[4] = {i0.x, i0.y, i0.z, i0.w};
        const float ig[4] = {i1.x, i1.y, i1.z, i1.w};
        const float ib[4] = {i2.x, i2.y, i2.z, i2.w};
        const float pr[4] = {p0.x, p0.y, p0.z, p0.w};
        const float pg[4] = {p1.x, p1.y, p1.z, p1.w};
        const float pb[4] = {p2.x, p2.y, p2.z, p2.w};
        const float tr[4] = {t0.x, t0.y, t0.z, t0.w};
        const float tg[4] = {t1.x, t1.y, t1.z, t1.w};
        const float tb[4] = {t2.x, t2.y, t2.z, t2.w};
        #pragma unroll
        for (int j = 0; j < 4; ++j) {
            const float il = luma_exact(ir[j], ig[j], ib[j]);
            if (il < 1.0f) {
                int bin = (int)floorf(__fmul_rn(il, 16.0f));
                bin = min(max(bin, 0), NBINS - 1);
                s += luma_exact(pr[j], pg[j], pb[j])
                   + luma_exact(tr[j], tg[j], tb[j]) + (float)bin;
            }
        }
    }
    #pragma unroll
    for (int o = 32; o; o >>= 1) s += __shfl_down(s, o);
    if ((threadIdx.x & 63) == 0) ws[blockIdx.x * 4 + (threadIdx.x >> 6)] = s;
}

// ---------- real stage1: R1-style colliding 48-word histogram ----------
__global__ __launch_bounds__(256) void tm_stage1(
    const float4* __restrict__ pred, const float4* __restrict__ target,
    const float4* __restrict__ input, float* __restrict__ partials,
    int G, int rows)
{
    __shared__ float h[NCOL];
    const int t = threadIdx.x;
    if (t < NCOL) h[t] = 0.0f;
    __syncthreads();

    const int T = gridDim.x * 256;
    for (int g = blockIdx.x * 256 + t; g < G; g += T) {
        const int a = (g >> 16) * (3 * CH4) + (g & (CH4 - 1));
        const float4 i0 = input[a],  i1 = input[a + CH4],  i2 = input[a + 2 * CH4];
        const float4 p0 = pred[a],   p1 = pred[a + CH4],   p2 = pred[a + 2 * CH4];
        const float4 t0 = target[a], t1 = target[a + CH4], t2 = target[a + 2 * CH4];
        const float ir[4] = {i0.x, i0.y, i0.z, i0.w};
        const float ig[4] = {i1.x, i1.y, i1.z, i1.w};
        const float ib[4] = {i2.x, i2.y, i2.z, i2.w};
        const float pr[4] = {p0.x, p0.y, p0.z, p0.w};
        const float pg[4] = {p1.x, p1.y, p1.z, p1.w};
        const float pb[4] = {p2.x, p2.y, p2.z, p2.w};
        const float tr[4] = {t0.x, t0.y, t0.z, t0.w};
        const float tg[4] = {t1.x, t1.y, t1.z, t1.w};
        const float tb[4] = {t2.x, t2.y, t2.z, t2.w};
        #pragma unroll
        for (int j = 0; j < 4; ++j) {
            const float il = luma_exact(ir[j], ig[j], ib[j]);
            if (il < 1.0f) {
                int bin = (int)floorf(__fmul_rn(il, 16.0f));
                bin = min(max(bin, 0), NBINS - 1);
                const float pl = luma_exact(pr[j], pg[j], pb[j]);
                const float tl = luma_exact(tr[j], tg[j], tb[j]);
                atomicAdd(&h[bin], 1.0f);
                atomicAdd(&h[NBINS + bin], pl);
                atomicAdd(&h[2 * NBINS + bin], tl);
            }
        }
    }

    __syncthreads();
    if (t < NCOL) partials[t * rows + blockIdx.x] = h[t];
}

__global__ __launch_bounds__(768) void tm_stage2(
    const float4* __restrict__ partials4, float* __restrict__ out, int rows4)
{
    __shared__ double col[NCOL];
    const int t = threadIdx.x;          // 768 = 48 cols x 16 threads
    const int c = t >> 4;
    const int l = t & 15;
    double s = 0.0;
    for (int k = l; k < rows4; k += 16) {
        const float4 v = partials4[c * rows4 + k];
        s += (double)v.x + (double)v.y + (double)v.z + (double)v.w;
    }
    #pragma unroll
    for (int k = 8; k; k >>= 1) s += __shfl_down(s, k, 16);
    if (l == 0) col[c] = s;
    __syncthreads();
    if (t == 0) {
        double acc = 0.0;
        #pragma unroll
        for (int i = 0; i < NBINS; ++i) {
            const double cnt = col[i];
            if (cnt > 0.0)
                acc += fabs(col[NBINS + i] / cnt - col[2 * NBINS + i] / cnt);
        }
        out[0] = (float)(acc / (double)NBINS);
    }
}

extern "C" void kernel_launch(void* const* d_in, const int* in_sizes, int n_in,
                              void* d_out, int out_size, void* d_ws, size_t ws_size,
                              hipStream_t stream) {
    const float* pred   = (const float*)d_in[0];
    const float* target = (const float*)d_in[1];
    const float* input  = (const float*)d_in[2];

    const int n4 = in_sizes[0] / 4;    // float4 per tensor
    const int G  = in_sizes[0] / 12;   // pixel float4-groups

    int blocks = 2048;
    const size_t maxRows = ws_size / (NCOL * sizeof(float));
    if ((size_t)blocks > maxRows) blocks = (int)maxRows;
    if (blocks < 1) blocks = 1;
    const int rows = (blocks + 3) & ~3;
    float* ws = (float*)d_ws;          // diag sums land here, overwritten by stage1

    // --- diagnostics (results discarded; overwritten by real stage1) ---
    ab_read3<<<blocks, 256, 0, stream>>>(
        (const float4*)pred, (const float4*)target, (const float4*)input, ws, n4);
    ab_read9<<<blocks, 256, 0, stream>>>(
        (const float4*)pred, (const float4*)target, (const float4*)input, ws, G);
    ab_nolds<<<blocks, 256, 0, stream>>>(
        (const float4*)pred, (const float4*)target, (const float4*)input, ws, G);

    // --- real computation ---
    tm_stage1<<<blocks, 256, 0, stream>>>(
        (const float4*)pred, (const float4*)target, (const float4*)input,
        ws, G, rows);
    tm_stage2<<<1, 768, 0, stream>>>((const float4*)ws, (float*)d_out, rows / 4);
}

// Round 6
// 68.333 us; speedup vs baseline: 2.2659x; 2.2659x over previous
//
#include <hip/hip_runtime.h>
#include <hip/hip_bf16.h>

// ToneMappingCurveLoss: luma-binned mean-difference loss.
// Inputs: pred, target, input_img: [16, 3, 512, 512] f32. Output: 1 f32 scalar.
// Reformulated: per bin need only count and dsum = sum(pl - tl), since
// |psum/c - tsum/c| == |dsum|/c. Accumulate both IN REGISTERS (no LDS/atomics
// in the hot loop): dsum via unrolled 16-way select, count via ballot+popc.

#define CH4 65536         // HW/4 (float4 groups per channel)
#define NBINS 16
#define NCOL 32           // partial columns: 16 counts + 16 dsums

__device__ __forceinline__ float luma_exact(float r, float g, float b) {
    // match numpy/jax f32 evaluation order, no FMA contraction
    return __fadd_rn(__fadd_rn(__fmul_rn(0.299f, r), __fmul_rn(0.587f, g)),
                     __fmul_rn(0.114f, b));
}

// ---------- diagnostic: stage1's 9-stream pattern, pure read ----------
__global__ __launch_bounds__(256) void ab_read9(
    const float4* __restrict__ pred, const float4* __restrict__ target,
    const float4* __restrict__ input, float* __restrict__ ws, int G)
{
    float s = 0.0f;
    const int T = gridDim.x * 256;
    for (int g = blockIdx.x * 256 + threadIdx.x; g < G; g += T) {
        const int a = (g >> 16) * (3 * CH4) + (g & (CH4 - 1));
        const float4 i0 = input[a],  i1 = input[a + CH4],  i2 = input[a + 2 * CH4];
        const float4 p0 = pred[a],   p1 = pred[a + CH4],   p2 = pred[a + 2 * CH4];
        const float4 t0 = target[a], t1 = target[a + CH4], t2 = target[a + 2 * CH4];
        s += i0.x + i0.y + i0.z + i0.w + i1.x + i1.y + i1.z + i1.w
           + i2.x + i2.y + i2.z + i2.w + p0.x + p0.y + p0.z + p0.w
           + p1.x + p1.y + p1.z + p1.w + p2.x + p2.y + p2.z + p2.w
           + t0.x + t0.y + t0.z + t0.w + t1.x + t1.y + t1.z + t1.w
           + t2.x + t2.y + t2.z + t2.w;
    }
    #pragma unroll
    for (int o = 32; o; o >>= 1) s += __shfl_down(s, o);
    if ((threadIdx.x & 63) == 0) ws[blockIdx.x * 4 + (threadIdx.x >> 6)] = s;
}

// ---------- stage1: register-resident binning, no LDS in hot loop ----------
__global__ __launch_bounds__(256) void tm_stage1(
    const float4* __restrict__ pred, const float4* __restrict__ target,
    const float4* __restrict__ input,
    float* __restrict__ partials,   // column-major [NCOL][rows]
    int G, int rows)
{
    __shared__ float red[4][NCOL];  // per-wave partials, combined at block end
    const int t = threadIdx.x;
    const int lane = t & 63;
    const int wid = t >> 6;

    float ds[NBINS];
    int cnt[NBINS];
    #pragma unroll
    for (int b = 0; b < NBINS; ++b) { ds[b] = 0.0f; cnt[b] = 0; }

    const int T = gridDim.x * 256;
    for (int g = blockIdx.x * 256 + t; g < G; g += T) {
        const int a = (g >> 16) * (3 * CH4) + (g & (CH4 - 1));
        const float4 i0 = input[a],  i1 = input[a + CH4],  i2 = input[a + 2 * CH4];
        const float4 p0 = pred[a],   p1 = pred[a + CH4],   p2 = pred[a + 2 * CH4];
        const float4 t0 = target[a], t1 = target[a + CH4], t2 = target[a + 2 * CH4];
        const float ir[4] = {i0.x, i0.y, i0.z, i0.w};
        const float ig[4] = {i1.x, i1.y, i1.z, i1.w};
        const float ib[4] = {i2.x, i2.y, i2.z, i2.w};
        const float pr[4] = {p0.x, p0.y, p0.z, p0.w};
        const float pg[4] = {p1.x, p1.y, p1.z, p1.w};
        const float pb[4] = {p2.x, p2.y, p2.z, p2.w};
        const float tr[4] = {t0.x, t0.y, t0.z, t0.w};
        const float tg[4] = {t1.x, t1.y, t1.z, t1.w};
        const float tb[4] = {t2.x, t2.y, t2.z, t2.w};

        #pragma unroll
        for (int j = 0; j < 4; ++j) {
            const float il = luma_exact(ir[j], ig[j], ib[j]);
            int bin = (int)floorf(__fmul_rn(il, 16.0f));
            bin = min(max(bin, 0), NBINS - 1);
            if (il >= 1.0f) bin = NBINS;          // excluded (matches no b)
            const float d = luma_exact(pr[j], pg[j], pb[j])
                          - luma_exact(tr[j], tg[j], tb[j]);
            #pragma unroll
            for (int b = 0; b < NBINS; ++b) {
                const bool m = (bin == b);
                cnt[b] += (int)__popcll(__ballot(m));   // wave-uniform count
                ds[b]  += m ? d : 0.0f;                 // per-lane dsum
            }
        }
    }

    // wave-reduce ds; cnt is already wave-uniform (every lane holds the total)
    #pragma unroll
    for (int b = 0; b < NBINS; ++b) {
        float v = ds[b];
        v += __shfl_down(v, 32);
        v += __shfl_down(v, 16);
        v += __shfl_down(v, 8);
        v += __shfl_down(v, 4);
        v += __shfl_down(v, 2);
        v += __shfl_down(v, 1);
        if (lane == 0) {
            red[wid][b] = (float)cnt[b];   // exact: cnt <= 2048 per block
            red[wid][NBINS + b] = v;
        }
    }
    __syncthreads();
    if (t < NCOL) {
        const float s = red[0][t] + red[1][t] + red[2][t] + red[3][t];
        partials[t * rows + blockIdx.x] = s;
    }
}

__global__ __launch_bounds__(512) void tm_stage2(
    const float4* __restrict__ partials4,  // column-major [NCOL][rows/4]
    float* __restrict__ out, int rows4)
{
    __shared__ double col[NCOL];
    const int t = threadIdx.x;          // 512 = 32 cols x 16 threads
    const int c = t >> 4;
    const int l = t & 15;

    double s = 0.0;
    for (int k = l; k < rows4; k += 16) {
        const float4 v = partials4[c * rows4 + k];
        s += (double)v.x + (double)v.y + (double)v.z + (double)v.w;
    }
    #pragma unroll
    for (int k = 8; k; k >>= 1) s += __shfl_down(s, k, 16);
    if (l == 0) col[c] = s;
    __syncthreads();

    if (t == 0) {
        double acc = 0.0;
        #pragma unroll
        for (int i = 0; i < NBINS; ++i) {
            const double cnt = col[i];
            if (cnt > 0.0) acc += fabs(col[NBINS + i]) / cnt;
        }
        out[0] = (float)(acc / (double)NBINS);
    }
}

extern "C" void kernel_launch(void* const* d_in, const int* in_sizes, int n_in,
                              void* d_out, int out_size, void* d_ws, size_t ws_size,
                              hipStream_t stream) {
    const float* pred   = (const float*)d_in[0];
    const float* target = (const float*)d_in[1];
    const float* input  = (const float*)d_in[2];

    const int G = in_sizes[0] / 12;    // pixel float4-groups (1048576 here)

    int blocks = 2048;                 // 8 blocks/CU, 2 groups/thread
    const size_t need = (size_t)(NCOL * 2048 + 2048 * 4) * sizeof(float);
    if (ws_size < need) blocks = 1024; // defensive; ws has been >=384KB so far
    const int rows = (blocks + 3) & ~3;
    float* partials = (float*)d_ws;
    float* diag = partials + (size_t)NCOL * rows;   // diagnostic scratch after

    // diagnostic: pure-read floor with identical access pattern
    ab_read9<<<blocks, 256, 0, stream>>>(
        (const float4*)pred, (const float4*)target, (const float4*)input, diag, G);

    tm_stage1<<<blocks, 256, 0, stream>>>(
        (const float4*)pred, (const float4*)target, (const float4*)input,
        partials, G, rows);
    tm_stage2<<<1, 512, 0, stream>>>(
        (const float4*)partials, (float*)d_out, rows / 4);
}

// Round 7
// 46.831 us; speedup vs baseline: 3.3062x; 1.4591x over previous
//
#include <hip/hip_runtime.h>
#include <hip/hip_bf16.h>

// ToneMappingCurveLoss: luma-binned mean-difference loss.
// Inputs: pred, target, input_img: [16, 3, 512, 512] f32. Output: 1 f32 scalar.
// Per bin only count and dsum = sum(pl - tl) are needed, since
// |psum/c - tsum/c| == |dsum|/c. Both accumulate IN REGISTERS (no LDS or
// atomics in the hot loop): dsum via unrolled 16-way select, count via
// ballot+popc (wave-uniform). Block partials -> stage2 final reduce.

#define CH4 65536         // HW/4 (float4 groups per channel)
#define NBINS 16
#define NCOL 32           // partial columns: 16 counts + 16 dsums

__device__ __forceinline__ float luma_exact(float r, float g, float b) {
    // match numpy/jax f32 evaluation order, no FMA contraction
    return __fadd_rn(__fadd_rn(__fmul_rn(0.299f, r), __fmul_rn(0.587f, g)),
                     __fmul_rn(0.114f, b));
}

// ---------- stage1: register-resident binning, no LDS in hot loop ----------
__global__ __launch_bounds__(256) void tm_stage1(
    const float4* __restrict__ pred, const float4* __restrict__ target,
    const float4* __restrict__ input,
    float* __restrict__ partials,   // column-major [NCOL][rows]
    int G, int rows)
{
    __shared__ float red[4][NCOL];  // per-wave partials, combined at block end
    const int t = threadIdx.x;
    const int lane = t & 63;
    const int wid = t >> 6;

    float ds[NBINS];
    int cnt[NBINS];
    #pragma unroll
    for (int b = 0; b < NBINS; ++b) { ds[b] = 0.0f; cnt[b] = 0; }

    const int T = gridDim.x * 256;
    for (int g = blockIdx.x * 256 + t; g < G; g += T) {
        const int a = (g >> 16) * (3 * CH4) + (g & (CH4 - 1));
        const float4 i0 = input[a],  i1 = input[a + CH4],  i2 = input[a + 2 * CH4];
        const float4 p0 = pred[a],   p1 = pred[a + CH4],   p2 = pred[a + 2 * CH4];
        const float4 t0 = target[a], t1 = target[a + CH4], t2 = target[a + 2 * CH4];
        const float ir[4] = {i0.x, i0.y, i0.z, i0.w};
        const float ig[4] = {i1.x, i1.y, i1.z, i1.w};
        const float ib[4] = {i2.x, i2.y, i2.z, i2.w};
        const float pr[4] = {p0.x, p0.y, p0.z, p0.w};
        const float pg[4] = {p1.x, p1.y, p1.z, p1.w};
        const float pb[4] = {p2.x, p2.y, p2.z, p2.w};
        const float tr[4] = {t0.x, t0.y, t0.z, t0.w};
        const float tg[4] = {t1.x, t1.y, t1.z, t1.w};
        const float tb[4] = {t2.x, t2.y, t2.z, t2.w};

        #pragma unroll
        for (int j = 0; j < 4; ++j) {
            const float il = luma_exact(ir[j], ig[j], ib[j]);
            int bin = (int)floorf(__fmul_rn(il, 16.0f));
            bin = min(max(bin, 0), NBINS - 1);
            if (il >= 1.0f) bin = NBINS;          // excluded (matches no b)
            const float d = luma_exact(pr[j], pg[j], pb[j])
                          - luma_exact(tr[j], tg[j], tb[j]);
            #pragma unroll
            for (int b = 0; b < NBINS; ++b) {
                const bool m = (bin == b);
                cnt[b] += (int)__popcll(__ballot(m));   // wave-uniform count
                ds[b]  += m ? d : 0.0f;                 // per-lane dsum
            }
        }
    }

    // wave-reduce ds; cnt is already wave-uniform (every lane holds the total)
    #pragma unroll
    for (int b = 0; b < NBINS; ++b) {
        float v = ds[b];
        v += __shfl_down(v, 32);
        v += __shfl_down(v, 16);
        v += __shfl_down(v, 8);
        v += __shfl_down(v, 4);
        v += __shfl_down(v, 2);
        v += __shfl_down(v, 1);
        if (lane == 0) {
            red[wid][b] = (float)cnt[b];   // exact: cnt <= 2048 per block
            red[wid][NBINS + b] = v;
        }
    }
    __syncthreads();
    if (t < NCOL) {
        const float s = red[0][t] + red[1][t] + red[2][t] + red[3][t];
        partials[t * rows + blockIdx.x] = s;
    }
}

__global__ __launch_bounds__(512) void tm_stage2(
    const float4* __restrict__ partials4,  // column-major [NCOL][rows/4]
    float* __restrict__ out, int rows4)
{
    __shared__ double col[NCOL];
    const int t = threadIdx.x;          // 512 = 32 cols x 16 threads
    const int c = t >> 4;
    const int l = t & 15;

    double s = 0.0;
    for (int k = l; k < rows4; k += 16) {
        const float4 v = partials4[c * rows4 + k];
        s += (double)v.x + (double)v.y + (double)v.z + (double)v.w;
    }
    #pragma unroll
    for (int k = 8; k; k >>= 1) s += __shfl_down(s, k, 16);
    if (l == 0) col[c] = s;
    __syncthreads();

    if (t == 0) {
        double acc = 0.0;
        #pragma unroll
        for (int i = 0; i < NBINS; ++i) {
            const double cnt = col[i];
            if (cnt > 0.0) acc += fabs(col[NBINS + i]) / cnt;
        }
        out[0] = (float)(acc / (double)NBINS);
    }
}

extern "C" void kernel_launch(void* const* d_in, const int* in_sizes, int n_in,
                              void* d_out, int out_size, void* d_ws, size_t ws_size,
                              hipStream_t stream) {
    const float* pred   = (const float*)d_in[0];
    const float* target = (const float*)d_in[1];
    const float* input  = (const float*)d_in[2];

    const int G = in_sizes[0] / 12;    // pixel float4-groups (1048576 here)

    int blocks = 2048;                 // 8 blocks/CU, 2 groups/thread
    const size_t maxRows = ws_size / (NCOL * sizeof(float));
    if ((size_t)blocks > maxRows) blocks = (int)maxRows;
    if (blocks < 1) blocks = 1;
    const int rows = (blocks + 3) & ~3;
    float* partials = (float*)d_ws;

    tm_stage1<<<blocks, 256, 0, stream>>>(
        (const float4*)pred, (const float4*)target, (const float4*)input,
        partials, G, rows);
    tm_stage2<<<1, 512, 0, stream>>>(
        (const float4*)partials, (float*)d_out, rows / 4);
}

// Round 8
// 41.482 us; speedup vs baseline: 3.7325x; 1.1289x over previous
//
#include <hip/hip_runtime.h>
#include <hip/hip_bf16.h>

// ToneMappingCurveLoss: luma-binned mean-difference loss.
// Inputs: pred, target, input_img: [16, 3, 512, 512] f32. Output: 1 f32 scalar.
// |psum/c - tsum/c| == |sum(pl-tl)|/c  -> per bin accumulate only count and
// dsum. Hot loop: nontemporal 16B loads (bypass L3 fill path), 3 phases
// (input->bins, pred->pl, target->accumulate). Accumulation: per-THREAD LDS
// slot dsh[bin][tid] (no atomics, bank-conflict-free) + byte-packed counts
// in two u64 registers. Block partials -> stage2 f64 reduce.

#define CH4 65536         // HW/4 (float4 groups per channel)
#define NBINS 16
#define NCOL 32           // partial columns: 16 counts + 16 dsums

typedef float f4 __attribute__((ext_vector_type(4)));

__device__ __forceinline__ float luma_exact(float r, float g, float b) {
    // match numpy/jax f32 evaluation order, no FMA contraction
    return __fadd_rn(__fadd_rn(__fmul_rn(0.299f, r), __fmul_rn(0.587f, g)),
                     __fmul_rn(0.114f, b));
}

__global__ __launch_bounds__(256) void tm_stage1(
    const f4* __restrict__ pred, const f4* __restrict__ target,
    const f4* __restrict__ input,
    float* __restrict__ partials,   // column-major [NCOL][rows]
    int G, int rows)
{
    __shared__ float dsh[NBINS * 256];              // 16 KB: [bin][tid]
    __shared__ unsigned long long cl[256], ch[256]; // 4 KB: packed counts
    const int t = threadIdx.x;

    #pragma unroll
    for (int k = 0; k < NBINS; ++k) dsh[k * 256 + t] = 0.0f;
    __syncthreads();

    unsigned long long cLo = 0ULL, cHi = 0ULL;  // bins 0-7 / 8-15, 8b each

    const int T = gridDim.x * 256;
    for (int g0 = blockIdx.x * 256 + t; g0 < G; g0 += 2 * T) {
        const int g1 = g0 + T;
        const bool ok1 = (g1 < G);
        const int a0 = (g0 >> 16) * (3 * CH4) + (g0 & (CH4 - 1));
        const int a1 = ok1 ? (g1 >> 16) * (3 * CH4) + (g1 & (CH4 - 1)) : a0;

        // ---- phase A: input -> 8 bins (4-bit packed) + exclusion mask ----
        const f4 iA0 = __builtin_nontemporal_load(&input[a0]);
        const f4 iA1 = __builtin_nontemporal_load(&input[a0 + CH4]);
        const f4 iA2 = __builtin_nontemporal_load(&input[a0 + 2 * CH4]);
        const f4 iB0 = __builtin_nontemporal_load(&input[a1]);
        const f4 iB1 = __builtin_nontemporal_load(&input[a1 + CH4]);
        const f4 iB2 = __builtin_nontemporal_load(&input[a1 + 2 * CH4]);

        unsigned bpack = 0u, excl = ok1 ? 0u : 0xF0u;
        #pragma unroll
        for (int j = 0; j < 4; ++j) {
            const float ilA = luma_exact(iA0[j], iA1[j], iA2[j]);
            int bA = (int)floorf(__fmul_rn(ilA, 16.0f));
            bA = min(max(bA, 0), NBINS - 1);
            bpack |= (unsigned)bA << (4 * j);
            excl |= (ilA >= 1.0f ? 1u : 0u) << j;

            const float ilB = luma_exact(iB0[j], iB1[j], iB2[j]);
            int bB = (int)floorf(__fmul_rn(ilB, 16.0f));
            bB = min(max(bB, 0), NBINS - 1);
            bpack |= (unsigned)bB << (4 * (j + 4));
            excl |= (ilB >= 1.0f ? 1u : 0u) << (j + 4);
        }

        // ---- phase B: pred -> pl[8] ----
        const f4 pA0 = __builtin_nontemporal_load(&pred[a0]);
        const f4 pA1 = __builtin_nontemporal_load(&pred[a0 + CH4]);
        const f4 pA2 = __builtin_nontemporal_load(&pred[a0 + 2 * CH4]);
        const f4 pB0 = __builtin_nontemporal_load(&pred[a1]);
        const f4 pB1 = __builtin_nontemporal_load(&pred[a1 + CH4]);
        const f4 pB2 = __builtin_nontemporal_load(&pred[a1 + 2 * CH4]);
        float pl[8];
        #pragma unroll
        for (int j = 0; j < 4; ++j) {
            pl[j]     = luma_exact(pA0[j], pA1[j], pA2[j]);
            pl[j + 4] = luma_exact(pB0[j], pB1[j], pB2[j]);
        }

        // ---- phase C: target -> d, accumulate ----
        const f4 tA0 = __builtin_nontemporal_load(&target[a0]);
        const f4 tA1 = __builtin_nontemporal_load(&target[a0 + CH4]);
        const f4 tA2 = __builtin_nontemporal_load(&target[a0 + 2 * CH4]);
        const f4 tB0 = __builtin_nontemporal_load(&target[a1]);
        const f4 tB1 = __builtin_nontemporal_load(&target[a1 + CH4]);
        const f4 tB2 = __builtin_nontemporal_load(&target[a1 + 2 * CH4]);

        #pragma unroll
        for (int j = 0; j < 4; ++j) {
            {
                const float tlA = luma_exact(tA0[j], tA1[j], tA2[j]);
                if (!((excl >> j) & 1u)) {
                    const int b = (int)((bpack >> (4 * j)) & 0xFu);
                    dsh[b * 256 + t] += pl[j] - tlA;
                    const unsigned long long inc = 1ULL << ((b & 7) * 8);
                    if (b < 8) cLo += inc; else cHi += inc;
                }
            }
            {
                const float tlB = luma_exact(tB0[j], tB1[j], tB2[j]);
                if (!((excl >> (j + 4)) & 1u)) {
                    const int b = (int)((bpack >> (4 * (j + 4))) & 0xFu);
                    dsh[b * 256 + t] += pl[j + 4] - tlB;
                    const unsigned long long inc = 1ULL << ((b & 7) * 8);
                    if (b < 8) cLo += inc; else cHi += inc;
                }
            }
        }
    }

    cl[t] = cLo; ch[t] = cHi;
    __syncthreads();

    // Epilogue: thread t reduces bin b = t>>4 over thread-strip l = t&15.
    const int b = t >> 4, l = t & 15;
    float s = 0.0f; int c = 0;
    #pragma unroll
    for (int k = 0; k < 16; ++k) {
        s += dsh[b * 256 + k * 16 + l];          // 4-way LDS conflict, tiny
        const unsigned long long packed = (b < 8) ? cl[k * 16 + l] : ch[k * 16 + l];
        c += (int)((packed >> ((b & 7) * 8)) & 0xFFULL);
    }
    #pragma unroll
    for (int k = 8; k; k >>= 1) {
        s += __shfl_down(s, k, 16);
        c += __shfl_down(c, k, 16);
    }
    if (l == 0) {
        partials[b * rows + blockIdx.x] = (float)c;          // cols 0..15
        partials[(NBINS + b) * rows + blockIdx.x] = s;       // cols 16..31
    }
}

__global__ __launch_bounds__(512) void tm_stage2(
    const float4* __restrict__ partials4,  // column-major [NCOL][rows/4]
    float* __restrict__ out, int rows4)
{
    __shared__ double col[NCOL];
    const int t = threadIdx.x;          // 512 = 32 cols x 16 threads
    const int c = t >> 4;
    const int l = t & 15;

    double s = 0.0;
    for (int k = l; k < rows4; k += 16) {
        const float4 v = partials4[c * rows4 + k];
        s += (double)v.x + (double)v.y + (double)v.z + (double)v.w;
    }
    #pragma unroll
    for (int k = 8; k; k >>= 1) s += __shfl_down(s, k, 16);
    if (l == 0) col[c] = s;
    __syncthreads();

    if (t == 0) {
        double acc = 0.0;
        #pragma unroll
        for (int i = 0; i < NBINS; ++i) {
            const double cnt = col[i];
            if (cnt > 0.0) acc += fabs(col[NBINS + i]) / cnt;
        }
        out[0] = (float)(acc / (double)NBINS);
    }
}

extern "C" void kernel_launch(void* const* d_in, const int* in_sizes, int n_in,
                              void* d_out, int out_size, void* d_ws, size_t ws_size,
                              hipStream_t stream) {
    const float* pred   = (const float*)d_in[0];
    const float* target = (const float*)d_in[1];
    const float* input  = (const float*)d_in[2];

    const int G = in_sizes[0] / 12;    // pixel float4-groups (1048576 here)

    int blocks = 2048;                 // 8 blocks/CU, 2 groups/thread
    const size_t maxRows = ws_size / (NCOL * sizeof(float));
    if ((size_t)blocks > maxRows) blocks = (int)maxRows;
    if (blocks < 1) blocks = 1;
    const int rows = (blocks + 3) & ~3;
    float* partials = (float*)d_ws;

    tm_stage1<<<blocks, 256, 0, stream>>>(
        (const f4*)pred, (const f4*)target, (const f4*)input,
        partials, G, rows);
    tm_stage2<<<1, 512, 0, stream>>>(
        (const float4*)partials, (float*)d_out, rows / 4);
}